// Round 11
// baseline (177.531 us; speedup 1.0000x reference)
//
#include <hip/hip_runtime.h>

#define BH 64    // output rows per band
#define NB 16    // bands per plane (1024/BH)

typedef float f32x4 __attribute__((ext_vector_type(4)));  // native vector for nt-store

__device__ __forceinline__ int reflect_idx(int i, int n) {
    // jnp.pad mode="reflect" (border not repeated); offsets stay < 2n-2.
    if (i < 0) i = -i;
    if (i >= n) i = 2 * n - 2 - i;
    return i;
}

__device__ __forceinline__ float4 ld4(const float* p) {
    return *reinterpret_cast<const float4*>(p);
}

// Ring slot: own 16B B-word + wave-edge halo words (valid only in lanes 0/63).
struct Slot { float4 B, Ae, Ce; };

// PURE loads, nothing consumed at issue site. Only 1 full-wave load; halo loads
// are exec-masked to the 2 wave-boundary lanes (1-2 cache lines).
__device__ __forceinline__ Slot load_slot(const float* __restrict__ row, int x0,
                                          bool welo, bool wehi) {
    Slot s;
    s.B = ld4(row + x0);
    if (welo) s.Ae = ld4(row + x0 - 4);   // lane 0 of wave, not image edge
    if (wehi) s.Ce = ld4(row + x0 + 4);   // lane 63 of wave, not image edge
    return s;
}

// Consume: neighbor columns via intra-wave shuffles (DS pipe), edge fixups, 7-tap sums.
__device__ __forceinline__ float4 hsum_slot(const Slot& s,
                                            bool welo, bool wehi, bool xlo, bool xhi) {
    const float4 B = s.B;
    float rm3 = __shfl_up(B.y, 1);    // col x0-3 (lane-1's B.y)
    float rm2 = __shfl_up(B.z, 1);    // col x0-2
    float rm1 = __shfl_up(B.w, 1);    // col x0-1
    float rp1 = __shfl_down(B.x, 1);  // col x0+4 (lane+1's B.x)
    float rp2 = __shfl_down(B.y, 1);  // col x0+5
    float rp3 = __shfl_down(B.z, 1);  // col x0+6
    if (welo) { rm3 = s.Ae.y; rm2 = s.Ae.z; rm1 = s.Ae.w; }
    if (xlo)  { rm3 = B.w;    rm2 = B.z;    rm1 = B.y;    }  // cols -3..-1 -> 3,2,1
    if (wehi) { rp1 = s.Ce.x; rp2 = s.Ce.y; rp3 = s.Ce.z; }
    if (xhi)  { rp1 = B.z;    rp2 = B.y;    rp3 = B.x;    }  // cols W..W+2 -> W-2..W-4
    float h0 = rm3 + rm2 + rm1 + B.x + B.y + B.z + B.w;      // cols x0-3..x0+3
    float h1 = h0 - rm3 + rp1;
    float h2 = h1 - rm2 + rp2;
    float h3 = h2 - rm1 + rp3;
    return make_float4(h0, h1, h2, h3);
}

__global__ __launch_bounds__(256, 4) void boxblur_kernel(const float* __restrict__ in,
                                                         float* __restrict__ out,
                                                         int H, int W, int cpx) {
    // bijective XCD-chunked swizzle: adjacent bands (sharing halo rows) stay on one XCD
    const int bid = blockIdx.x;
    const int sbid = (bid & 7) * cpx + (bid >> 3);
    const int plane = sbid >> 4;            // NB=16 bands per plane
    const int y0 = (sbid & 15) * BH;

    const float* __restrict__ src = in + (size_t)plane * H * W;
    float* __restrict__ dst = out + (size_t)plane * H * W;

    const int tid = threadIdx.x;
    const int x0 = tid * 4;                 // 256 threads cover 1024 cols
    const int lane = tid & 63;
    const bool xlo = (tid == 0), xhi = (tid == 255);
    const bool welo = (lane == 0) && !xlo;  // wave-start, needs left halo from memory
    const bool wehi = (lane == 63) && !xhi; // wave-end, needs right halo from memory

    // ---- prologue: hsum ring slots 1..7 = input rows y0-4 .. y0+2 ----
    float4 hr[8];
    float4 vs = make_float4(0.f, 0.f, 0.f, 0.f);
#pragma unroll
    for (int j = 0; j < 7; ++j) {
        const float* rp = src + (size_t)reflect_idx(y0 - 4 + j, H) * W;
        float4 h = hsum_slot(load_slot(rp, x0, welo, wehi), welo, wehi, xlo, xhi);
        hr[1 + j] = h;
        vs.x += h.x; vs.y += h.y; vs.z += h.z; vs.w += h.w;
    }

    // ---- fill raw ring (depth 4): rows y0+3 .. y0+6 ----
    Slot s0 = load_slot(src + (size_t)reflect_idx(y0 + 3, H) * W, x0, welo, wehi);
    Slot s1 = load_slot(src + (size_t)reflect_idx(y0 + 4, H) * W, x0, welo, wehi);
    Slot s2 = load_slot(src + (size_t)reflect_idx(y0 + 5, H) * W, x0, welo, wehi);
    Slot s3 = load_slot(src + (size_t)reflect_idx(y0 + 6, H) * W, x0, welo, wehi);

    const float inv = 1.0f / 49.0f;
    float* orow = dst + (size_t)y0 * W + x0;
    int yload = y0 + 7;                     // next input row to fetch (uniform scalar)

    // Phase p (output row r, p = r&7): consume raw slot (p&3), slide vertical sum,
    // nt-store, reissue slot's loads for row r+4 (stays in flight 4 phases).
#define PHASE_CORE(p, praw, pn)                                                     \
        float4 hn = hsum_slot(s##praw, welo, wehi, xlo, xhi);                       \
        vs.x += hn.x - hr[pn].x; vs.y += hn.y - hr[pn].y;                           \
        vs.z += hn.z - hr[pn].z; vs.w += hn.w - hr[pn].w;                           \
        hr[p] = hn;                                                                 \
        f32x4 o = { vs.x * inv, vs.y * inv, vs.z * inv, vs.w * inv };               \
        __builtin_nontemporal_store(o, reinterpret_cast<f32x4*>(orow));             \
        orow += W;

#define PHASE(p, praw, pn)                                                          \
    {                                                                               \
        PHASE_CORE(p, praw, pn)                                                     \
        s##praw = load_slot(src + (size_t)reflect_idx(yload, H) * W, x0, welo, wehi); \
        ++yload;                                                                    \
    }

#define PHASE_NL(p, praw, pn)  { PHASE_CORE(p, praw, pn) }   // no reload (tail peel)

    for (int it = 0; it < BH / 8 - 1; ++it) {   // 7 macro-iters x 8 rows
        PHASE(0, 0, 1) PHASE(1, 1, 2) PHASE(2, 2, 3) PHASE(3, 3, 4)
        PHASE(4, 0, 5) PHASE(5, 1, 6) PHASE(6, 2, 7) PHASE(7, 3, 0)
    }
    // final macro-iter: last 4 phases' reloads would never be consumed -> peeled
    PHASE(0, 0, 1) PHASE(1, 1, 2) PHASE(2, 2, 3) PHASE(3, 3, 4)
    PHASE_NL(4, 0, 5) PHASE_NL(5, 1, 6) PHASE_NL(6, 2, 7) PHASE_NL(7, 3, 0)
#undef PHASE
#undef PHASE_NL
#undef PHASE_CORE
}

extern "C" void kernel_launch(void* const* d_in, const int* in_sizes, int n_in,
                              void* d_out, int out_size, void* d_ws, size_t ws_size,
                              hipStream_t stream) {
    const float* x = (const float*)d_in[0];
    float* out = (float*)d_out;
    const int H = 1024, W = 1024;
    const int NC = 32 * 3;
    const int nwg = NC * NB;            // 96 * 16 = 1536 blocks (divisible by 8)
    dim3 grid(nwg);
    dim3 block(256);
    boxblur_kernel<<<grid, block, 0, stream>>>(x, out, H, W, nwg / 8);
}

// Round 12
// 171.291 us; speedup vs baseline: 1.0364x; 1.0364x over previous
//
#include <hip/hip_runtime.h>

#define BH 128   // output rows per band
#define NB 8     // bands per plane (1024/BH)

typedef float f32x4 __attribute__((ext_vector_type(4)));  // native vector for nt-store

__device__ __forceinline__ int reflect_idx(int i, int n) {
    // jnp.pad mode="reflect" (border not repeated); offsets stay < 2n-2.
    if (i < 0) i = -i;
    if (i >= n) i = 2 * n - 2 - i;
    return i;
}

__device__ __forceinline__ float4 ld4(const float* p) {
    return *reinterpret_cast<const float4*>(p);
}

// Ring slot: own 16B B-word + wave-edge halo words (valid only in lanes 0/63).
struct Slot { float4 B, Ae, Ce; };

// PURE loads, nothing consumed at issue site. Only 1 full-wave load; halo loads
// are exec-masked to the 2 wave-boundary lanes (1-2 cache lines).
__device__ __forceinline__ Slot load_slot(const float* __restrict__ row, int x0,
                                          bool welo, bool wehi) {
    Slot s;
    s.B = ld4(row + x0);
    if (welo) s.Ae = ld4(row + x0 - 4);   // lane 0 of wave, not image edge
    if (wehi) s.Ce = ld4(row + x0 + 4);   // lane 63 of wave, not image edge
    return s;
}

// Consume: neighbor columns via intra-wave shuffles (DS pipe), edge fixups, 7-tap sums.
__device__ __forceinline__ float4 hsum_slot(const Slot& s,
                                            bool welo, bool wehi, bool xlo, bool xhi) {
    const float4 B = s.B;
    float rm3 = __shfl_up(B.y, 1);    // col x0-3 (lane-1's B.y)
    float rm2 = __shfl_up(B.z, 1);    // col x0-2
    float rm1 = __shfl_up(B.w, 1);    // col x0-1
    float rp1 = __shfl_down(B.x, 1);  // col x0+4 (lane+1's B.x)
    float rp2 = __shfl_down(B.y, 1);  // col x0+5
    float rp3 = __shfl_down(B.z, 1);  // col x0+6
    if (welo) { rm3 = s.Ae.y; rm2 = s.Ae.z; rm1 = s.Ae.w; }
    if (xlo)  { rm3 = B.w;    rm2 = B.z;    rm1 = B.y;    }  // cols -3..-1 -> 3,2,1
    if (wehi) { rp1 = s.Ce.x; rp2 = s.Ce.y; rp3 = s.Ce.z; }
    if (xhi)  { rp1 = B.z;    rp2 = B.y;    rp3 = B.x;    }  // cols W..W+2 -> W-2..W-4
    float h0 = rm3 + rm2 + rm1 + B.x + B.y + B.z + B.w;      // cols x0-3..x0+3
    float h1 = h0 - rm3 + rp1;
    float h2 = h1 - rm2 + rp2;
    float h3 = h2 - rm1 + rp3;
    return make_float4(h0, h1, h2, h3);
}

__global__ __launch_bounds__(256, 3) void boxblur_kernel(const float* __restrict__ in,
                                                         float* __restrict__ out,
                                                         int H, int W, int cpx) {
    // bijective XCD-chunked swizzle: adjacent bands (sharing halo rows) stay on one XCD
    const int bid = blockIdx.x;
    const int sbid = (bid & 7) * cpx + (bid >> 3);
    const int plane = sbid >> 3;            // NB=8 bands per plane
    const int y0 = (sbid & 7) * BH;

    const float* __restrict__ src = in + (size_t)plane * H * W;
    float* __restrict__ dst = out + (size_t)plane * H * W;

    const int tid = threadIdx.x;
    const int x0 = tid * 4;                 // 256 threads cover 1024 cols
    const int lane = tid & 63;
    const bool xlo = (tid == 0), xhi = (tid == 255);
    const bool welo = (lane == 0) && !xlo;  // wave-start, needs left halo from memory
    const bool wehi = (lane == 63) && !xhi; // wave-end, needs right halo from memory

    // ---- prologue: hsum ring slots 1..7 = input rows y0-4 .. y0+2 ----
    float4 hr[8];
    float4 vs = make_float4(0.f, 0.f, 0.f, 0.f);
#pragma unroll
    for (int j = 0; j < 7; ++j) {
        const float* rp = src + (size_t)reflect_idx(y0 - 4 + j, H) * W;
        float4 h = hsum_slot(load_slot(rp, x0, welo, wehi), welo, wehi, xlo, xhi);
        hr[1 + j] = h;
        vs.x += h.x; vs.y += h.y; vs.z += h.z; vs.w += h.w;
    }

    // ---- fill raw ring (depth 8): rows y0+3 .. y0+10 ----
    Slot s0 = load_slot(src + (size_t)reflect_idx(y0 + 3, H) * W, x0, welo, wehi);
    Slot s1 = load_slot(src + (size_t)reflect_idx(y0 + 4, H) * W, x0, welo, wehi);
    Slot s2 = load_slot(src + (size_t)reflect_idx(y0 + 5, H) * W, x0, welo, wehi);
    Slot s3 = load_slot(src + (size_t)reflect_idx(y0 + 6, H) * W, x0, welo, wehi);
    Slot s4 = load_slot(src + (size_t)reflect_idx(y0 + 7, H) * W, x0, welo, wehi);
    Slot s5 = load_slot(src + (size_t)reflect_idx(y0 + 8, H) * W, x0, welo, wehi);
    Slot s6 = load_slot(src + (size_t)reflect_idx(y0 + 9, H) * W, x0, welo, wehi);
    Slot s7 = load_slot(src + (size_t)reflect_idx(y0 + 10, H) * W, x0, welo, wehi);

    const float inv = 1.0f / 49.0f;
    float* orow = dst + (size_t)y0 * W + x0;
    int yload = y0 + 11;                    // next input row to fetch (uniform scalar)

    // Phase p (output row r, p = r&7): consume raw slot p, slide vertical sum,
    // nt-store, reissue slot's loads for row r+11 (stays in flight 8 phases).
#define PHASE_CORE(p, pn)                                                           \
        float4 hn = hsum_slot(s##p, welo, wehi, xlo, xhi);                          \
        vs.x += hn.x - hr[pn].x; vs.y += hn.y - hr[pn].y;                           \
        vs.z += hn.z - hr[pn].z; vs.w += hn.w - hr[pn].w;                           \
        hr[p] = hn;                                                                 \
        f32x4 o = { vs.x * inv, vs.y * inv, vs.z * inv, vs.w * inv };               \
        __builtin_nontemporal_store(o, reinterpret_cast<f32x4*>(orow));             \
        orow += W;

#define PHASE(p, pn)                                                                \
    {                                                                               \
        PHASE_CORE(p, pn)                                                           \
        s##p = load_slot(src + (size_t)reflect_idx(yload, H) * W, x0, welo, wehi);  \
        ++yload;                                                                    \
    }

#define PHASE_NL(p, pn)  { PHASE_CORE(p, pn) }   // no reload (tail peel)

    for (int it = 0; it < BH / 8 - 1; ++it) {   // 15 macro-iters x 8 rows
        PHASE(0, 1) PHASE(1, 2) PHASE(2, 3) PHASE(3, 4)
        PHASE(4, 5) PHASE(5, 6) PHASE(6, 7) PHASE(7, 0)
    }
    // final macro-iter: reloads would never be consumed -> peeled
    PHASE_NL(0, 1) PHASE_NL(1, 2) PHASE_NL(2, 3) PHASE_NL(3, 4)
    PHASE_NL(4, 5) PHASE_NL(5, 6) PHASE_NL(6, 7) PHASE_NL(7, 0)
#undef PHASE
#undef PHASE_NL
#undef PHASE_CORE
}

extern "C" void kernel_launch(void* const* d_in, const int* in_sizes, int n_in,
                              void* d_out, int out_size, void* d_ws, size_t ws_size,
                              hipStream_t stream) {
    const float* x = (const float*)d_in[0];
    float* out = (float*)d_out;
    const int H = 1024, W = 1024;
    const int NC = 32 * 3;
    const int nwg = NC * NB;            // 96 * 8 = 768 blocks (divisible by 8)
    dim3 grid(nwg);
    dim3 block(256);
    boxblur_kernel<<<grid, block, 0, stream>>>(x, out, H, W, nwg / 8);
}

// Round 13
// 169.225 us; speedup vs baseline: 1.0491x; 1.0122x over previous
//
#include <hip/hip_runtime.h>

#define BH 128   // output rows per band
#define NB 8     // bands per plane (1024/BH)

__device__ __forceinline__ int reflect_idx(int i, int n) {
    // jnp.pad mode="reflect" (border not repeated); offsets stay < 2n-2.
    if (i < 0) i = -i;
    if (i >= n) i = 2 * n - 2 - i;
    return i;
}

__device__ __forceinline__ float4 ld4(const float* p) {
    return *reinterpret_cast<const float4*>(p);
}

// Ring slot: own 16B B-word + wave-edge halo words (valid only in lanes 0/63).
struct Slot { float4 B, Ae, Ce; };

// PURE loads, nothing consumed at issue site. Only 1 full-wave load; halo loads
// are exec-masked to the 2 wave-boundary lanes (1-2 cache lines).
__device__ __forceinline__ Slot load_slot(const float* __restrict__ row, int x0,
                                          bool welo, bool wehi) {
    Slot s;
    s.B = ld4(row + x0);
    if (welo) s.Ae = ld4(row + x0 - 4);   // lane 0 of wave, not image edge
    if (wehi) s.Ce = ld4(row + x0 + 4);   // lane 63 of wave, not image edge
    return s;
}

// Consume: neighbor columns via intra-wave shuffles (DS pipe), edge fixups, 7-tap sums.
__device__ __forceinline__ float4 hsum_slot(const Slot& s,
                                            bool welo, bool wehi, bool xlo, bool xhi) {
    const float4 B = s.B;
    float rm3 = __shfl_up(B.y, 1);    // col x0-3 (lane-1's B.y)
    float rm2 = __shfl_up(B.z, 1);    // col x0-2
    float rm1 = __shfl_up(B.w, 1);    // col x0-1
    float rp1 = __shfl_down(B.x, 1);  // col x0+4 (lane+1's B.x)
    float rp2 = __shfl_down(B.y, 1);  // col x0+5
    float rp3 = __shfl_down(B.z, 1);  // col x0+6
    if (welo) { rm3 = s.Ae.y; rm2 = s.Ae.z; rm1 = s.Ae.w; }
    if (xlo)  { rm3 = B.w;    rm2 = B.z;    rm1 = B.y;    }  // cols -3..-1 -> 3,2,1
    if (wehi) { rp1 = s.Ce.x; rp2 = s.Ce.y; rp3 = s.Ce.z; }
    if (xhi)  { rp1 = B.z;    rp2 = B.y;    rp3 = B.x;    }  // cols W..W+2 -> W-2..W-4
    float h0 = rm3 + rm2 + rm1 + B.x + B.y + B.z + B.w;      // cols x0-3..x0+3
    float h1 = h0 - rm3 + rp1;
    float h2 = h1 - rm2 + rp2;
    float h3 = h2 - rm1 + rp3;
    return make_float4(h0, h1, h2, h3);
}

__global__ __launch_bounds__(256, 3) void boxblur_kernel(const float* __restrict__ in,
                                                         float* __restrict__ out,
                                                         int H, int W, int cpx) {
    // bijective XCD-chunked swizzle: adjacent bands (sharing halo rows) stay on one XCD
    const int bid = blockIdx.x;
    const int sbid = (bid & 7) * cpx + (bid >> 3);
    const int plane = sbid >> 3;            // NB=8 bands per plane
    const int y0 = (sbid & 7) * BH;

    const float* __restrict__ src = in + (size_t)plane * H * W;
    float* __restrict__ dst = out + (size_t)plane * H * W;

    const int tid = threadIdx.x;
    const int x0 = tid * 4;                 // 256 threads cover 1024 cols
    const int lane = tid & 63;
    const bool xlo = (tid == 0), xhi = (tid == 255);
    const bool welo = (lane == 0) && !xlo;  // wave-start, needs left halo from memory
    const bool wehi = (lane == 63) && !xhi; // wave-end, needs right halo from memory

    // ---- prologue: hsum ring slots 1..7 = input rows y0-4 .. y0+2 ----
    float4 hr[8];
    float4 vs = make_float4(0.f, 0.f, 0.f, 0.f);
#pragma unroll
    for (int j = 0; j < 7; ++j) {
        const float* rp = src + (size_t)reflect_idx(y0 - 4 + j, H) * W;
        float4 h = hsum_slot(load_slot(rp, x0, welo, wehi), welo, wehi, xlo, xhi);
        hr[1 + j] = h;
        vs.x += h.x; vs.y += h.y; vs.z += h.z; vs.w += h.w;
    }

    // ---- fill raw ring (depth 4): rows y0+3 .. y0+6 ----
    Slot s0 = load_slot(src + (size_t)reflect_idx(y0 + 3, H) * W, x0, welo, wehi);
    Slot s1 = load_slot(src + (size_t)reflect_idx(y0 + 4, H) * W, x0, welo, wehi);
    Slot s2 = load_slot(src + (size_t)reflect_idx(y0 + 5, H) * W, x0, welo, wehi);
    Slot s3 = load_slot(src + (size_t)reflect_idx(y0 + 6, H) * W, x0, welo, wehi);

    const float inv = 1.0f / 49.0f;
    float* orow = dst + (size_t)y0 * W + x0;
    int yload = y0 + 7;                     // next input row to fetch (uniform scalar)

    // Phase p (output row r, p = r&7): consume raw slot (p&3), slide vertical sum,
    // NORMAL store (acks in L2 write-back fast; keeps the in-order vmcnt FIFO from
    // gating load consumption on HBM store acks), reissue slot's loads for row r+4.
#define PHASE_CORE(p, praw, pn)                                                     \
        float4 hn = hsum_slot(s##praw, welo, wehi, xlo, xhi);                       \
        vs.x += hn.x - hr[pn].x; vs.y += hn.y - hr[pn].y;                           \
        vs.z += hn.z - hr[pn].z; vs.w += hn.w - hr[pn].w;                           \
        hr[p] = hn;                                                                 \
        *reinterpret_cast<float4*>(orow) =                                          \
            make_float4(vs.x * inv, vs.y * inv, vs.z * inv, vs.w * inv);            \
        orow += W;

#define PHASE(p, praw, pn)                                                          \
    {                                                                               \
        PHASE_CORE(p, praw, pn)                                                     \
        s##praw = load_slot(src + (size_t)reflect_idx(yload, H) * W, x0, welo, wehi); \
        ++yload;                                                                    \
    }

#define PHASE_NL(p, praw, pn)  { PHASE_CORE(p, praw, pn) }   // no reload (tail peel)

    for (int it = 0; it < BH / 8 - 1; ++it) {   // 15 macro-iters x 8 rows
        PHASE(0, 0, 1) PHASE(1, 1, 2) PHASE(2, 2, 3) PHASE(3, 3, 4)
        PHASE(4, 0, 5) PHASE(5, 1, 6) PHASE(6, 2, 7) PHASE(7, 3, 0)
    }
    // final macro-iter: last 4 phases' reloads would never be consumed -> peeled
    PHASE(0, 0, 1) PHASE(1, 1, 2) PHASE(2, 2, 3) PHASE(3, 3, 4)
    PHASE_NL(4, 0, 5) PHASE_NL(5, 1, 6) PHASE_NL(6, 2, 7) PHASE_NL(7, 3, 0)
#undef PHASE
#undef PHASE_NL
#undef PHASE_CORE
}

extern "C" void kernel_launch(void* const* d_in, const int* in_sizes, int n_in,
                              void* d_out, int out_size, void* d_ws, size_t ws_size,
                              hipStream_t stream) {
    const float* x = (const float*)d_in[0];
    float* out = (float*)d_out;
    const int H = 1024, W = 1024;
    const int NC = 32 * 3;
    const int nwg = NC * NB;            // 96 * 8 = 768 blocks (divisible by 8)
    dim3 grid(nwg);
    dim3 block(256);
    boxblur_kernel<<<grid, block, 0, stream>>>(x, out, H, W, nwg / 8);
}

// Round 14
// 158.153 us; speedup vs baseline: 1.1225x; 1.0700x over previous
//
#include <hip/hip_runtime.h>

#define BH 64    // output rows per band
#define NB 16    // bands per plane (1024/BH)

typedef float f32x4 __attribute__((ext_vector_type(4)));  // native vector for nt-store

__device__ __forceinline__ int reflect_idx(int i, int n) {
    // jnp.pad mode="reflect" (border not repeated); offsets stay < 2n-2.
    if (i < 0) i = -i;
    if (i >= n) i = 2 * n - 2 - i;
    return i;
}

__device__ __forceinline__ float4 ld4(const float* p) {
    return *reinterpret_cast<const float4*>(p);
}

// Ring slot: own 16B B-word + wave-edge halo words (valid only in lanes 0/63).
struct Slot { float4 B, Ae, Ce; };

// PURE loads, nothing consumed at issue site. Only 1 full-wave load; halo loads
// are exec-masked to the 2 wave-boundary lanes (1-2 cache lines).
__device__ __forceinline__ Slot load_slot(const float* __restrict__ row, int x0,
                                          bool welo, bool wehi) {
    Slot s;
    s.B = ld4(row + x0);
    if (welo) s.Ae = ld4(row + x0 - 4);   // lane 0 of wave, not image edge
    if (wehi) s.Ce = ld4(row + x0 + 4);   // lane 63 of wave, not image edge
    return s;
}

// Consume: neighbor columns via intra-wave shuffles (DS pipe), edge fixups, 7-tap sums.
__device__ __forceinline__ float4 hsum_slot(const Slot& s,
                                            bool welo, bool wehi, bool xlo, bool xhi) {
    const float4 B = s.B;
    float rm3 = __shfl_up(B.y, 1);    // col x0-3 (lane-1's B.y)
    float rm2 = __shfl_up(B.z, 1);    // col x0-2
    float rm1 = __shfl_up(B.w, 1);    // col x0-1
    float rp1 = __shfl_down(B.x, 1);  // col x0+4 (lane+1's B.x)
    float rp2 = __shfl_down(B.y, 1);  // col x0+5
    float rp3 = __shfl_down(B.z, 1);  // col x0+6
    if (welo) { rm3 = s.Ae.y; rm2 = s.Ae.z; rm1 = s.Ae.w; }
    if (xlo)  { rm3 = B.w;    rm2 = B.z;    rm1 = B.y;    }  // cols -3..-1 -> 3,2,1
    if (wehi) { rp1 = s.Ce.x; rp2 = s.Ce.y; rp3 = s.Ce.z; }
    if (xhi)  { rp1 = B.z;    rp2 = B.y;    rp3 = B.x;    }  // cols W..W+2 -> W-2..W-4
    float h0 = rm3 + rm2 + rm1 + B.x + B.y + B.z + B.w;      // cols x0-3..x0+3
    float h1 = h0 - rm3 + rp1;
    float h2 = h1 - rm2 + rp2;
    float h3 = h2 - rm1 + rp3;
    return make_float4(h0, h1, h2, h3);
}

__global__ __launch_bounds__(256, 3) void boxblur_kernel(const float* __restrict__ in,
                                                         float* __restrict__ out,
                                                         int H, int W, int cpx) {
    // bijective XCD-chunked swizzle: adjacent bands (sharing halo rows) stay on one XCD
    const int bid = blockIdx.x;
    const int sbid = (bid & 7) * cpx + (bid >> 3);
    const int plane = sbid >> 4;            // NB=16 bands per plane
    const int y0 = (sbid & 15) * BH;

    const float* __restrict__ src = in + (size_t)plane * H * W;
    float* __restrict__ dst = out + (size_t)plane * H * W;

    const int tid = threadIdx.x;
    const int x0 = tid * 4;                 // 256 threads cover 1024 cols
    const int lane = tid & 63;
    const bool xlo = (tid == 0), xhi = (tid == 255);
    const bool welo = (lane == 0) && !xlo;  // wave-start, needs left halo from memory
    const bool wehi = (lane == 63) && !xhi; // wave-end, needs right halo from memory

    // ---- prologue: hsum ring slots 1..7 = input rows y0-4 .. y0+2 ----
    float4 hr[8];
    float4 vs = make_float4(0.f, 0.f, 0.f, 0.f);
#pragma unroll
    for (int j = 0; j < 7; ++j) {
        const float* rp = src + (size_t)reflect_idx(y0 - 4 + j, H) * W;
        float4 h = hsum_slot(load_slot(rp, x0, welo, wehi), welo, wehi, xlo, xhi);
        hr[1 + j] = h;
        vs.x += h.x; vs.y += h.y; vs.z += h.z; vs.w += h.w;
    }

    // ---- fill raw ring (depth 4): rows y0+3 .. y0+6 ----
    Slot s0 = load_slot(src + (size_t)reflect_idx(y0 + 3, H) * W, x0, welo, wehi);
    Slot s1 = load_slot(src + (size_t)reflect_idx(y0 + 4, H) * W, x0, welo, wehi);
    Slot s2 = load_slot(src + (size_t)reflect_idx(y0 + 5, H) * W, x0, welo, wehi);
    Slot s3 = load_slot(src + (size_t)reflect_idx(y0 + 6, H) * W, x0, welo, wehi);

    const float inv = 1.0f / 49.0f;
    float* orow = dst + (size_t)y0 * W + x0;
    int yload = y0 + 7;                     // next input row to fetch (uniform scalar)

    // Phase p (output row r, p = r&7): consume raw slot (p&3), slide vertical sum,
    // nt-store, reissue slot's loads for row r+4 (stays in flight 4 phases).
#define PHASE_CORE(p, praw, pn)                                                     \
        float4 hn = hsum_slot(s##praw, welo, wehi, xlo, xhi);                       \
        vs.x += hn.x - hr[pn].x; vs.y += hn.y - hr[pn].y;                           \
        vs.z += hn.z - hr[pn].z; vs.w += hn.w - hr[pn].w;                           \
        hr[p] = hn;                                                                 \
        f32x4 o = { vs.x * inv, vs.y * inv, vs.z * inv, vs.w * inv };               \
        __builtin_nontemporal_store(o, reinterpret_cast<f32x4*>(orow));             \
        orow += W;

#define PHASE(p, praw, pn)                                                          \
    {                                                                               \
        PHASE_CORE(p, praw, pn)                                                     \
        s##praw = load_slot(src + (size_t)reflect_idx(yload, H) * W, x0, welo, wehi); \
        ++yload;                                                                    \
    }

#define PHASE_NL(p, praw, pn)  { PHASE_CORE(p, praw, pn) }   // no reload (tail peel)

    for (int it = 0; it < BH / 8 - 1; ++it) {   // 7 macro-iters x 8 rows
        PHASE(0, 0, 1) PHASE(1, 1, 2) PHASE(2, 2, 3) PHASE(3, 3, 4)
        PHASE(4, 0, 5) PHASE(5, 1, 6) PHASE(6, 2, 7) PHASE(7, 3, 0)
    }
    // final macro-iter: last 4 phases' reloads would never be consumed -> peeled
    PHASE(0, 0, 1) PHASE(1, 1, 2) PHASE(2, 2, 3) PHASE(3, 3, 4)
    PHASE_NL(4, 0, 5) PHASE_NL(5, 1, 6) PHASE_NL(6, 2, 7) PHASE_NL(7, 3, 0)
#undef PHASE
#undef PHASE_NL
#undef PHASE_CORE
}

extern "C" void kernel_launch(void* const* d_in, const int* in_sizes, int n_in,
                              void* d_out, int out_size, void* d_ws, size_t ws_size,
                              hipStream_t stream) {
    const float* x = (const float*)d_in[0];
    float* out = (float*)d_out;
    const int H = 1024, W = 1024;
    const int NC = 32 * 3;
    const int nwg = NC * NB;            // 96 * 16 = 1536 blocks (divisible by 8)
    dim3 grid(nwg);
    dim3 block(256);
    boxblur_kernel<<<grid, block, 0, stream>>>(x, out, H, W, nwg / 8);
}

// Round 15
// 155.361 us; speedup vs baseline: 1.1427x; 1.0180x over previous
//
#include <hip/hip_runtime.h>

#define BH 32    // output rows per band
#define NB 32    // bands per plane (1024/BH)

typedef float f32x4 __attribute__((ext_vector_type(4)));  // native vector for nt-store

__device__ __forceinline__ int reflect_idx(int i, int n) {
    // jnp.pad mode="reflect" (border not repeated); offsets stay < 2n-2.
    if (i < 0) i = -i;
    if (i >= n) i = 2 * n - 2 - i;
    return i;
}

__device__ __forceinline__ float4 ld4(const float* p) {
    return *reinterpret_cast<const float4*>(p);
}

// Ring slot: own 16B B-word + wave-edge halo words (valid only in lanes 0/63).
struct Slot { float4 B, Ae, Ce; };

// PURE loads, nothing consumed at issue site. Only 1 full-wave load; halo loads
// are exec-masked to the 2 wave-boundary lanes (1-2 cache lines).
__device__ __forceinline__ Slot load_slot(const float* __restrict__ row, int x0,
                                          bool welo, bool wehi) {
    Slot s;
    s.B = ld4(row + x0);
    if (welo) s.Ae = ld4(row + x0 - 4);   // lane 0 of wave, not image edge
    if (wehi) s.Ce = ld4(row + x0 + 4);   // lane 63 of wave, not image edge
    return s;
}

// Consume: neighbor columns via intra-wave shuffles (DS pipe), edge fixups, 7-tap sums.
__device__ __forceinline__ float4 hsum_slot(const Slot& s,
                                            bool welo, bool wehi, bool xlo, bool xhi) {
    const float4 B = s.B;
    float rm3 = __shfl_up(B.y, 1);    // col x0-3 (lane-1's B.y)
    float rm2 = __shfl_up(B.z, 1);    // col x0-2
    float rm1 = __shfl_up(B.w, 1);    // col x0-1
    float rp1 = __shfl_down(B.x, 1);  // col x0+4 (lane+1's B.x)
    float rp2 = __shfl_down(B.y, 1);  // col x0+5
    float rp3 = __shfl_down(B.z, 1);  // col x0+6
    if (welo) { rm3 = s.Ae.y; rm2 = s.Ae.z; rm1 = s.Ae.w; }
    if (xlo)  { rm3 = B.w;    rm2 = B.z;    rm1 = B.y;    }  // cols -3..-1 -> 3,2,1
    if (wehi) { rp1 = s.Ce.x; rp2 = s.Ce.y; rp3 = s.Ce.z; }
    if (xhi)  { rp1 = B.z;    rp2 = B.y;    rp3 = B.x;    }  // cols W..W+2 -> W-2..W-4
    float h0 = rm3 + rm2 + rm1 + B.x + B.y + B.z + B.w;      // cols x0-3..x0+3
    float h1 = h0 - rm3 + rp1;
    float h2 = h1 - rm2 + rp2;
    float h3 = h2 - rm1 + rp3;
    return make_float4(h0, h1, h2, h3);
}

__global__ __launch_bounds__(256, 3) void boxblur_kernel(const float* __restrict__ in,
                                                         float* __restrict__ out,
                                                         int H, int W, int cpx) {
    // bijective XCD-chunked swizzle: adjacent bands (sharing halo rows) stay on one XCD
    const int bid = blockIdx.x;
    const int sbid = (bid & 7) * cpx + (bid >> 3);
    const int plane = sbid >> 5;            // NB=32 bands per plane
    const int y0 = (sbid & 31) * BH;

    const float* __restrict__ src = in + (size_t)plane * H * W;
    float* __restrict__ dst = out + (size_t)plane * H * W;

    const int tid = threadIdx.x;
    const int x0 = tid * 4;                 // 256 threads cover 1024 cols
    const int lane = tid & 63;
    const bool xlo = (tid == 0), xhi = (tid == 255);
    const bool welo = (lane == 0) && !xlo;  // wave-start, needs left halo from memory
    const bool wehi = (lane == 63) && !xhi; // wave-end, needs right halo from memory

    // ---- prologue: hsum ring slots 1..7 = input rows y0-4 .. y0+2 ----
    float4 hr[8];
    float4 vs = make_float4(0.f, 0.f, 0.f, 0.f);
#pragma unroll
    for (int j = 0; j < 7; ++j) {
        const float* rp = src + (size_t)reflect_idx(y0 - 4 + j, H) * W;
        float4 h = hsum_slot(load_slot(rp, x0, welo, wehi), welo, wehi, xlo, xhi);
        hr[1 + j] = h;
        vs.x += h.x; vs.y += h.y; vs.z += h.z; vs.w += h.w;
    }

    // ---- fill raw ring (depth 4): rows y0+3 .. y0+6 ----
    Slot s0 = load_slot(src + (size_t)reflect_idx(y0 + 3, H) * W, x0, welo, wehi);
    Slot s1 = load_slot(src + (size_t)reflect_idx(y0 + 4, H) * W, x0, welo, wehi);
    Slot s2 = load_slot(src + (size_t)reflect_idx(y0 + 5, H) * W, x0, welo, wehi);
    Slot s3 = load_slot(src + (size_t)reflect_idx(y0 + 6, H) * W, x0, welo, wehi);

    const float inv = 1.0f / 49.0f;
    float* orow = dst + (size_t)y0 * W + x0;
    int yload = y0 + 7;                     // next input row to fetch (uniform scalar)

    // Phase p (output row r, p = r&7): consume raw slot (p&3), slide vertical sum,
    // nt-store, reissue slot's loads for row r+4 (stays in flight 4 phases).
#define PHASE_CORE(p, praw, pn)                                                     \
        float4 hn = hsum_slot(s##praw, welo, wehi, xlo, xhi);                       \
        vs.x += hn.x - hr[pn].x; vs.y += hn.y - hr[pn].y;                           \
        vs.z += hn.z - hr[pn].z; vs.w += hn.w - hr[pn].w;                           \
        hr[p] = hn;                                                                 \
        f32x4 o = { vs.x * inv, vs.y * inv, vs.z * inv, vs.w * inv };               \
        __builtin_nontemporal_store(o, reinterpret_cast<f32x4*>(orow));             \
        orow += W;

#define PHASE(p, praw, pn)                                                          \
    {                                                                               \
        PHASE_CORE(p, praw, pn)                                                     \
        s##praw = load_slot(src + (size_t)reflect_idx(yload, H) * W, x0, welo, wehi); \
        ++yload;                                                                    \
    }

#define PHASE_NL(p, praw, pn)  { PHASE_CORE(p, praw, pn) }   // no reload (tail peel)

    for (int it = 0; it < BH / 8 - 1; ++it) {   // 3 macro-iters x 8 rows
        PHASE(0, 0, 1) PHASE(1, 1, 2) PHASE(2, 2, 3) PHASE(3, 3, 4)
        PHASE(4, 0, 5) PHASE(5, 1, 6) PHASE(6, 2, 7) PHASE(7, 3, 0)
    }
    // final macro-iter: last 4 phases' reloads would never be consumed -> peeled
    PHASE(0, 0, 1) PHASE(1, 1, 2) PHASE(2, 2, 3) PHASE(3, 3, 4)
    PHASE_NL(4, 0, 5) PHASE_NL(5, 1, 6) PHASE_NL(6, 2, 7) PHASE_NL(7, 3, 0)
#undef PHASE
#undef PHASE_NL
#undef PHASE_CORE
}

extern "C" void kernel_launch(void* const* d_in, const int* in_sizes, int n_in,
                              void* d_out, int out_size, void* d_ws, size_t ws_size,
                              hipStream_t stream) {
    const float* x = (const float*)d_in[0];
    float* out = (float*)d_out;
    const int H = 1024, W = 1024;
    const int NC = 32 * 3;
    const int nwg = NC * NB;            // 96 * 32 = 3072 blocks (divisible by 8)
    dim3 grid(nwg);
    dim3 block(256);
    boxblur_kernel<<<grid, block, 0, stream>>>(x, out, H, W, nwg / 8);
}